// Round 4
// baseline (347.043 us; speedup 1.0000x reference)
//
#include <hip/hip_runtime.h>

#define BATCH 4096
#define DM 768
#define LTOT 10240
#define NG 124

typedef __bf16 bf16x8 __attribute__((ext_vector_type(8)));
typedef short short8 __attribute__((ext_vector_type(8)));
typedef float f32x4 __attribute__((ext_vector_type(4)));

struct Ptr5 { const float* p[5]; };

__device__ __forceinline__ unsigned short f2bf(float f) {
    unsigned u = __builtin_bit_cast(unsigned, f);
    unsigned r = (u + 0x7FFFu + ((u >> 16) & 1u)) >> 16;   // RNE
    return (unsigned short)r;
}

__device__ __forceinline__ short8 pack8(float4 a, float4 b) {
    union { unsigned short u[8]; short8 s; } o;
    o.u[0] = f2bf(a.x); o.u[1] = f2bf(a.y); o.u[2] = f2bf(a.z); o.u[3] = f2bf(a.w);
    o.u[4] = f2bf(b.x); o.u[5] = f2bf(b.y); o.u[6] = f2bf(b.z); o.u[7] = f2bf(b.w);
    return o.s;
}

// ---------------- fat prep kernel (single dispatch, no atomics-needing-init) ----
// bx [0,32):       gate GEMM: relu(x@enc^T - b) -> gate_ws + d_out gates + slot stats
// bx [32,1952):    V{g}/U{g} conv (2048 float4/block), norm partial -> vslot/uslot
// bx [1952,2336):  x -> xb bf16 cast

__global__ __launch_bounds__(256) void prep_k(const float* __restrict__ x,
                                              Ptr5 vp, Ptr5 up, Ptr5 ep, Ptr5 bp,
                                              unsigned short* __restrict__ vb,
                                              unsigned short* __restrict__ w2t,
                                              unsigned short* __restrict__ xb,
                                              float* __restrict__ gate_ws,
                                              float* __restrict__ outg,
                                              float* __restrict__ vslot,
                                              float* __restrict__ uslot,
                                              float* __restrict__ gslot,
                                              float* __restrict__ aslot) {
    const int basen[5] = {0, 4, 12, 28, 60};
    int bx = blockIdx.x;
    int tid = threadIdx.x;
    if (bx < 32) {
        // ---- gate GEMM (M=128 rows per block, N=128 cols (124 valid), K=768) ----
        __shared__ unsigned short lA[128 * 64];
        __shared__ unsigned short lB[128 * 64];
        __shared__ float sgs[128];
        __shared__ float sac;
        int wave = tid >> 6, lane = tid & 63;
        int wm = wave >> 1, wn = wave & 1;
        int lan15 = lane & 15, quad = lane >> 4;
        int sw = lan15 & 7;
        int m0 = bx * 128;
        f32x4 acc[4][4] = {};
        for (int k0 = 0; k0 < DM; k0 += 64) {
            __syncthreads();
            #pragma unroll
            for (int i = 0; i < 4; i++) {
                int gidx = i * 256 + tid;           // granule index 0..1023
                int row = gidx >> 3, kb = gidx & 7;
                int r7 = row & 7;
                int la = (row >> 3) * 512 + r7 * 64 + (kb ^ r7) * 8;
                int sidx = (m0 + row) * 192 + (k0 >> 2) + kb * 2;
                float4 a0 = ((const float4*)x)[sidx];
                float4 a1 = ((const float4*)x)[sidx + 1];
                *(short8*)(lA + la) = pack8(a0, a1);
                float4 b0 = {0.f, 0.f, 0.f, 0.f}, b1 = {0.f, 0.f, 0.f, 0.f};
                if (row < NG) {
                    int g = (row < 4) ? 0 : (row < 12) ? 1 : (row < 28) ? 2 :
                            (row < 60) ? 3 : 4;
                    int ni = row - basen[g];
                    int eidx = ni * 192 + (k0 >> 2) + kb * 2;
                    b0 = ((const float4*)ep.p[g])[eidx];
                    b1 = ((const float4*)ep.p[g])[eidx + 1];
                }
                *(short8*)(lB + la) = pack8(b0, b1);
            }
            __syncthreads();
            #pragma unroll
            for (int kk = 0; kk < 2; kk++) {
                int kb = kk * 4 + quad;
                int kel = (kb ^ sw) * 8;
                bf16x8 af[4], bfr[4];
                #pragma unroll
                for (int t = 0; t < 4; t++) {
                    short8 ra = *(const short8*)(lA + (wm * 64 + t * 16 + lan15) * 64 + kel);
                    short8 rb = *(const short8*)(lB + (wn * 64 + t * 16 + lan15) * 64 + kel);
                    af[t]  = __builtin_bit_cast(bf16x8, ra);
                    bfr[t] = __builtin_bit_cast(bf16x8, rb);
                }
                #pragma unroll
                for (int mt = 0; mt < 4; mt++)
                    #pragma unroll
                    for (int nt = 0; nt < 4; nt++)
                        acc[mt][nt] = __builtin_amdgcn_mfma_f32_16x16x32_bf16(
                            af[mt], bfr[nt], acc[mt][nt], 0, 0, 0);
            }
        }
        if (tid < 128) sgs[tid] = 0.f;
        if (tid == 0) sac = 0.f;
        __syncthreads();
        const size_t baseg[5] = {3145730ull, 3145730ull + 16384, 3145730ull + 49152,
                                 3145730ull + 114688, 3145730ull + 245760};
        float cnt = 0.f;
        #pragma unroll
        for (int nt = 0; nt < 4; nt++) {
            int col = wn * 64 + nt * 16 + lan15;
            float cs = 0.f;
            if (col < NG) {
                int g = (col < 4) ? 0 : (col < 12) ? 1 : (col < 28) ? 2 :
                        (col < 60) ? 3 : 4;
                int ni = col - basen[g];
                int w = 4 << g;
                float bv = bp.p[g][ni];
                #pragma unroll
                for (int mt = 0; mt < 4; mt++) {
                    int r0 = m0 + wm * 64 + mt * 16 + quad * 4;
                    #pragma unroll
                    for (int rg = 0; rg < 4; rg++) {
                        float pre = acc[mt][nt][rg] - bv;
                        float gt = pre > 0.f ? pre : 0.f;
                        gate_ws[(size_t)(r0 + rg) * NG + col] = gt;
                        outg[baseg[g] + (size_t)(r0 + rg) * w + ni] = gt;
                        cs += gt;
                        if (pre > 0.f) cnt += 1.f;
                    }
                }
                cs += __shfl_xor(cs, 16);
                cs += __shfl_xor(cs, 32);
                if (quad == 0) atomicAdd(&sgs[col], cs);
            }
        }
        #pragma unroll
        for (int off = 32; off > 0; off >>= 1) cnt += __shfl_xor(cnt, off);
        if (lane == 0) atomicAdd(&sac, cnt);
        __syncthreads();
        if (tid < NG) gslot[bx * NG + tid] = sgs[tid];
        if (tid == 0) aslot[bx] = sac;
    } else if (bx < 1952) {
        // ---- streaming V/U conversion + norm slots ----
        __shared__ float swave[4];
        int cb = bx - 32;
        int isV = cb < 960;
        int wb = isV ? cb : cb - 960;       // 0..959
        int g = wb / 192;
        int within = wb - g * 192;
        const float* src = isV ? vp.p[g] : up.p[g];
        int r = 512 >> g, lr = 9 - g;
        float ss = 0.f;
        #pragma unroll
        for (int i = 0; i < 8; i++) {
            int j = within * 2048 + i * 256 + tid;
            float4 v = ((const float4*)src)[j];
            ss += v.x*v.x + v.y*v.y + v.z*v.z + v.w*v.w;
            ushort4 o;
            o.x = f2bf(v.x); o.y = f2bf(v.y); o.z = f2bf(v.z); o.w = f2bf(v.w);
            if (isV) {
                ((ushort4*)vb)[(size_t)(g * 192 + within) * 2048 + i * 256 + tid] = o;
            } else {
                int idx = j * 4;
                int rr = idx & (r - 1);
                int t2 = idx >> lr;
                int d  = t2 % DM;
                int n  = t2 / DM;
                size_t dst = (size_t)d * LTOT + (size_t)(g << 11) + (size_t)n * r + rr;
                *(ushort4*)(w2t + dst) = o;
            }
        }
        #pragma unroll
        for (int off = 32; off > 0; off >>= 1) ss += __shfl_down(ss, off);
        if ((tid & 63) == 0) swave[tid >> 6] = ss;
        __syncthreads();
        if (tid == 0) {
            float t = (swave[0] + swave[1]) + (swave[2] + swave[3]);
            (isV ? vslot : uslot)[wb] = t;
        }
    } else {
        // ---- x -> xb ----
        int base = (bx - 1952) * 2048;
        #pragma unroll
        for (int i = 0; i < 8; i++) {
            int j = base + i * 256 + tid;
            float4 v = ((const float4*)x)[j];
            ushort4 o;
            o.x = f2bf(v.x); o.y = f2bf(v.y); o.z = f2bf(v.z); o.w = f2bf(v.w);
            ((ushort4*)xb)[j] = o;
        }
    }
}

// ---------------- shared staging helper (XOR-swizzled async global->LDS) -------
template <int ROWS, int NT>
__device__ __forceinline__ void stage(const unsigned short* __restrict__ src, int ld,
                                      unsigned short* lds, int wv, int lane) {
    int rsub = lane >> 3;
    int colb = ((lane ^ rsub) & 7) * 8;
    #pragma unroll
    for (int i = 0; i < ROWS * 8 / NT; i++) {
        int c = i * (NT / 64) + wv;
        const unsigned short* gp = src + (size_t)(c * 8 + rsub) * ld + colb;
        __builtin_amdgcn_global_load_lds((const __attribute__((address_space(1))) void*)gp,
                                         (__attribute__((address_space(3))) void*)(lds + c * 512),
                                         16, 0, 0);
    }
}

// ---------------- GEMM1: 16x16x32 MFMA, gate + bf16 Hg LDS-transposed epilogue --
template <int BM, int BN, int NT>
__global__ __launch_bounds__(NT) void gemm_nt(const unsigned short* __restrict__ A,
                                              const unsigned short* __restrict__ Bm,
                                              int Kblk, int lda, int ldb,
                                              void* __restrict__ Cout,
                                              const float* __restrict__ gate, int ldc) {
    __shared__ unsigned short lA[BM * 64];
    __shared__ unsigned short lB[BN * 64];
    int tid = threadIdx.x, wave = tid >> 6, lane = tid & 63;
    constexpr int WN = BN / 64;
    int wm = wave / WN, wn = wave % WN;
    int m0 = blockIdx.x * BM, n0 = blockIdx.y * BN;    // m is the FAST grid dim
    A  += (size_t)m0 * lda;
    Bm += (size_t)n0 * ldb;
    f32x4 acc[4][4] = {};
    int lan15 = lane & 15, quad = lane >> 4;
    int sw = lan15 & 7;

    for (int k0 = 0; k0 < Kblk; k0 += 64) {
        stage<BM, NT>(A + k0, lda, lA, wave, lane);
        stage<BN, NT>(Bm + k0, ldb, lB, wave, lane);
        __syncthreads();
        #pragma unroll
        for (int kk = 0; kk < 2; kk++) {
            int kb = kk * 4 + quad;
            int kel = (kb ^ sw) * 8;
            bf16x8 af[4], bfr[4];
            #pragma unroll
            for (int t = 0; t < 4; t++) {
                short8 ra = *(const short8*)(lA + (size_t)(wm * 64 + t * 16 + lan15) * 64 + kel);
                short8 rb = *(const short8*)(lB + (size_t)(wn * 64 + t * 16 + lan15) * 64 + kel);
                af[t]  = __builtin_bit_cast(bf16x8, ra);
                bfr[t] = __builtin_bit_cast(bf16x8, rb);
            }
            #pragma unroll
            for (int mt = 0; mt < 4; mt++)
                #pragma unroll
                for (int nt = 0; nt < 4; nt++)
                    acc[mt][nt] = __builtin_amdgcn_mfma_f32_16x16x32_bf16(af[mt], bfr[nt],
                                                                          acc[mt][nt], 0, 0, 0);
        }
        __syncthreads();
    }

    const int basen[5] = {0, 4, 12, 28, 60};
    unsigned short* H = (unsigned short*)Cout;
    #pragma unroll
    for (int mt = 0; mt < 4; mt++) {
        __syncthreads();
        #pragma unroll
        for (int nt = 0; nt < 4; nt++) {
            int col = n0 + wn * 64 + nt * 16 + lan15;
            int g = col >> 11;
            int ngl = basen[g] + ((col & 2047) >> (9 - g));
            #pragma unroll
            for (int rg = 0; rg < 4; rg++) {
                int grow = m0 + wm * 64 + mt * 16 + quad * 4 + rg;
                float gv = gate[(size_t)grow * NG + ngl];
                lA[wave * 1024 + (quad * 4 + rg) * 64 + nt * 16 + lan15] =
                    f2bf(acc[mt][nt][rg] * gv);
            }
        }
        __syncthreads();
        #pragma unroll
        for (int i = 0; i < 2; i++) {
            int f = i * NT + tid;
            int R = f >> 5;
            int u = f & 31;
            int wv2 = ((R >> 4) << 2) + (u >> 3);
            short8 vread = *(const short8*)(lA + wv2 * 1024 + (R & 15) * 64 + (u & 7) * 8);
            int grow = m0 + (R >> 4) * 64 + mt * 16 + (R & 15);
            *(short8*)(H + (size_t)grow * ldc + n0 + u * 8) = vread;
        }
    }
}

// ---------------- GEMM2: phase-split counted-vmcnt pipeline (T3+T4) ------------
// 256x128 block, BK=32, 4 waves of 128x64 (acc[8][4]): 0.375 KB LDS-read/MFMA
// (vs 0.5 before). Two phases per K-tile; per-wave vmcnt sits at 6 outstanding
// global_load_lds, waits vmcnt(2)/vmcnt(4) — NEVER drains to 0 in the loop
// (the 1-phase vmcnt(0)+barrier drain was the measured ~2x-over-floor cost:
// 80 us vs 38 us LDS floor, MfmaUtil 35%). Double-buffered 48 KB LDS (static).
// Ledger (per wave, steady state): tile T set1 {A rows 0-63,128-191; all B} = 4
// loads issued at T-1.Q1; set2 {A rows 64-127,192-255} = 2 loads at T-1.Q2.
// Q1: vmcnt(2) leaves Tset2 in flight, waits Tset1. Q2: vmcnt(4) leaves T+1set1,
// waits Tset2. Stages are issued AFTER the phase barrier -> WAR on the buffer
// being overwritten is closed by that same barrier (prev readers' lgkmcnt'd
// ds_reads precede their barrier arrival).
__global__ __launch_bounds__(256, 2) void gemm2_nt(const unsigned short* __restrict__ A,
                                                   const unsigned short* __restrict__ Bm,
                                                   float* __restrict__ P) {
    __shared__ unsigned short lA[2][256 * 32];   // 2 x 16 KB
    __shared__ unsigned short lB[2][128 * 32];   // 2 x  8 KB
    int tid = threadIdx.x, wave = tid >> 6, lane = tid & 63;
    int wm = wave >> 1, wn = wave & 1;
    int lan15 = lane & 15, quad = lane >> 4;
    int kel = (quad ^ (lan15 & 3)) * 8;          // swizzled granule for frag reads
    int m0 = blockIdx.x * 256, n0 = blockIdx.y * 128;
    const unsigned short* Ab = A  + (size_t)m0 * LTOT + (size_t)blockIdx.z * 2048;
    const unsigned short* Bb = Bm + (size_t)n0 * LTOT + (size_t)blockIdx.z * 2048;
    int rsub = lane >> 2;                         // row within 16-row group
    int gofs = ((lane & 3) ^ (rsub & 3)) * 8;     // swizzled source granule (ushorts)

#define G2_STA(cur, kof, c) __builtin_amdgcn_global_load_lds( \
        (const __attribute__((address_space(1))) void*)(Ab + (size_t)((c) * 16 + rsub) * LTOT + (kof) + gofs), \
        (__attribute__((address_space(3))) void*)(&lA[cur][(c) * 512]), 16, 0, 0)
#define G2_STB(cur, kof, c) __builtin_amdgcn_global_load_lds( \
        (const __attribute__((address_space(1))) void*)(Bb + (size_t)((c) * 16 + rsub) * LTOT + (kof) + gofs), \
        (__attribute__((address_space(3))) void*)(&lB[cur][(c) * 512]), 16, 0, 0)

    f32x4 acc[8][4] = {};
    // prologue: tile 0 -> buf 0, in steady-state order (set1 then set2)
    G2_STA(0, 0, wave); G2_STA(0, 0, wave + 8); G2_STB(0, 0, wave); G2_STB(0, 0, wave + 4);
    G2_STA(0, 0, wave + 4); G2_STA(0, 0, wave + 12);

#define G2_TILE(cur, knext) { \
    asm volatile("s_waitcnt vmcnt(2)" ::: "memory"); \
    __builtin_amdgcn_s_barrier(); \
    asm volatile("" ::: "memory"); \
    G2_STA(cur ^ 1, knext, wave); G2_STA(cur ^ 1, knext, wave + 8); \
    G2_STB(cur ^ 1, knext, wave); G2_STB(cur ^ 1, knext, wave + 4); \
    bf16x8 bfr[4], af[4]; \
    _Pragma("unroll") for (int nt = 0; nt < 4; nt++) \
        bfr[nt] = __builtin_bit_cast(bf16x8, *(const short8*)(&lB[cur][(wn * 64 + nt * 16 + lan15) * 32 + kel])); \
    _Pragma("unroll") for (int mt = 0; mt < 4; mt++) \
        af[mt] = __builtin_bit_cast(bf16x8, *(const short8*)(&lA[cur][(wm * 128 + mt * 16 + lan15) * 32 + kel])); \
    __builtin_amdgcn_s_setprio(1); \
    _Pragma("unroll") for (int mt = 0; mt < 4; mt++) \
        _Pragma("unroll") for (int nt = 0; nt < 4; nt++) \
            acc[mt][nt] = __builtin_amdgcn_mfma_f32_16x16x32_bf16(af[mt], bfr[nt], acc[mt][nt], 0, 0, 0); \
    __builtin_amdgcn_s_setprio(0); \
    asm volatile("s_waitcnt vmcnt(4)" ::: "memory"); \
    __builtin_amdgcn_s_barrier(); \
    asm volatile("" ::: "memory"); \
    G2_STA(cur ^ 1, knext, wave + 4); G2_STA(cur ^ 1, knext, wave + 12); \
    _Pragma("unroll") for (int mt = 0; mt < 4; mt++) \
        af[mt] = __builtin_bit_cast(bf16x8, *(const short8*)(&lA[cur][(wm * 128 + 64 + mt * 16 + lan15) * 32 + kel])); \
    __builtin_amdgcn_s_setprio(1); \
    _Pragma("unroll") for (int mt = 0; mt < 4; mt++) \
        _Pragma("unroll") for (int nt = 0; nt < 4; nt++) \
            acc[4 + mt][nt] = __builtin_amdgcn_mfma_f32_16x16x32_bf16(af[mt], bfr[nt], acc[4 + mt][nt], 0, 0, 0); \
    __builtin_amdgcn_s_setprio(0); \
}

    for (int t2 = 0; t2 < 32; t2++) {
        int k0 = t2 * 64;
        G2_TILE(0, k0 + 32);
        int knext = (t2 == 31) ? (k0 + 32) : (k0 + 64);   // clamp: harmless re-stage
        G2_TILE(1, knext);
    }
#undef G2_TILE
#undef G2_STA
#undef G2_STB
    asm volatile("s_waitcnt vmcnt(0)" ::: "memory");

    float* Pz = P + (size_t)blockIdx.z * ((size_t)BATCH * DM);
    #pragma unroll
    for (int mt = 0; mt < 8; mt++) {
        #pragma unroll
        for (int rg = 0; rg < 4; rg++) {
            int row = m0 + wm * 128 + mt * 16 + quad * 4 + rg;
            float* pr = Pz + (size_t)row * DM + n0 + wn * 64 + lan15;
            #pragma unroll
            for (int nt = 0; nt < 4; nt++)
                pr[nt * 16] = acc[mt][nt][rg];
        }
    }
}

// ---------------- split-K (5-way) reduce + fused final stats (block 0) ---------

__global__ __launch_bounds__(256) void reduce_k(const float4* __restrict__ P,
                                                float4* __restrict__ out, int quarter,
                                                const float* __restrict__ vslot,
                                                const float* __restrict__ uslot,
                                                const float* __restrict__ gslot,
                                                const float* __restrict__ aslot,
                                                float* __restrict__ o2) {
    int i = blockIdx.x * 256 + threadIdx.x;
    float4 a = P[i], b = P[i + quarter], c = P[i + 2 * quarter], d = P[i + 3 * quarter];
    float4 e = P[i + 4 * quarter];
    float4 o;
    o.x = ((a.x + b.x) + (c.x + d.x)) + e.x;
    o.y = ((a.y + b.y) + (c.y + d.y)) + e.y;
    o.z = ((a.z + b.z) + (c.z + d.z)) + e.z;
    o.w = ((a.w + b.w) + (c.w + d.w)) + e.w;
    out[i] = o;
    if (blockIdx.x == 0) {
        __shared__ float sh[128];
        const int basen[5] = {0, 4, 12, 28, 60};
        int t = threadIdx.x;
        if (t < 128) {
            float v = 0.f;
            if (t < NG) {
                int g = (t < 4) ? 0 : (t < 12) ? 1 : (t < 28) ? 2 : (t < 60) ? 3 : 4;
                int nloc = t - basen[g];
                int bpseg = 48 >> g;
                float vs = 0.f, us = 0.f;
                int base = g * 192 + nloc * bpseg;
                for (int j = 0; j < bpseg; j++) { vs += vslot[base + j]; us += uslot[base + j]; }
                float gs = 0.f;
                for (int bb = 0; bb < 32; bb++) gs += gslot[bb * NG + t];
                float rr = (float)(512 >> g);
                float mean = gs * (1.0f / BATCH);
                float frob = sqrtf(us * vs) / sqrtf(768.0f * rr);
                v = tanhf(mean) * frob;
            }
            sh[t] = v;
        }
        if (t == 128) {
            float asum = 0.f;
            for (int bb = 0; bb < 32; bb++) asum += aslot[bb];
            o2[1] = asum * (1.0f / BATCH);
        }
        __syncthreads();
        for (int s = 64; s > 0; s >>= 1) {
            if (threadIdx.x < s) sh[threadIdx.x] += sh[threadIdx.x + s];
            __syncthreads();
        }
        if (threadIdx.x == 0) o2[0] = sh[0];
    }
}

// ---------------- launcher ----------------
// Workspace (proven ws_size >= 174 MB from prior rounds; this layout needs 163):
//   w2t (15.73) | slots (~0.03) | Hg (83.9) | partial 5*12.58 = 62.9
// xb/vb/gate_ws are ALIASED into the partial region: they are dead after gemm1,
// and partial is written only by gemm2 which runs after gemm1 (stream-ordered).
// Single-chunk only (CB == BATCH) — required by the aliasing.

extern "C" void kernel_launch(void* const* d_in, const int* in_sizes, int n_in,
                              void* d_out, int out_size, void* d_ws, size_t ws_size,
                              hipStream_t stream) {
    const float* x = (const float*)d_in[0];
    Ptr5 vp, up, ep, bp;
    for (int g = 0; g < 5; g++) {
        vp.p[g] = (const float*)d_in[1 + 4 * g];
        up.p[g] = (const float*)d_in[2 + 4 * g];
        ep.p[g] = (const float*)d_in[3 + 4 * g];
        bp.p[g] = (const float*)d_in[4 + 4 * g];
    }
    float* out = (float*)d_out;
    char* ws = (char*)d_ws;
    size_t off = 0;
    unsigned short* w2t  = (unsigned short*)(ws + off); off += (size_t)LTOT * DM * 2;
    float* vslot         = (float*)(ws + off);          off += 960 * 4;
    float* uslot         = (float*)(ws + off);          off += 960 * 4;
    float* gslot         = (float*)(ws + off);          off += 32 * NG * 4;
    float* aslot         = (float*)(ws + off);          off += 32 * 4 + 256;
    unsigned short* Hg   = (unsigned short*)(ws + off); off += (size_t)BATCH * LTOT * 2;
    float* partial       = (float*)(ws + off);          off += 5ull * BATCH * DM * 4;
    // aliases inside the partial region (24.1 MB used of 62.9):
    unsigned short* xb      = (unsigned short*)partial;
    unsigned short* vb      = (unsigned short*)((char*)partial + (size_t)BATCH * DM * 2);
    float* gate_ws          = (float*)((char*)partial + (size_t)BATCH * DM * 2
                                                      + (size_t)LTOT * DM * 2);

    prep_k<<<dim3(2336), 256, 0, stream>>>(
        x, vp, up, ep, bp, vb, w2t, xb, gate_ws, out,
        vslot, uslot, gslot, aslot);

    // GEMM1: Hg = gate .* (x @ V^T)   (M=4096, N=10240, K=768), m-fast grid
    gemm_nt<128, 256, 512><<<dim3(BATCH / 128, LTOT / 256, 1), 512, 0, stream>>>(
        xb, vb, DM, DM, DM, (void*)Hg, gate_ws, LTOT);
    // GEMM2: out = Hg @ W2   (M=4096, N=768, K=10240), split-K=5, pipelined
    gemm2_nt<<<dim3(BATCH / 256, DM / 128, 5), 256, 0, stream>>>(Hg, w2t, partial);
    // 5-way reduce + fused final stats (block 0)
    reduce_k<<<dim3(BATCH * DM / 4 / 256), 256, 0, stream>>>(
        (const float4*)partial, (float4*)out, BATCH * DM / 4,
        vslot, uslot, gslot, aslot, out + (size_t)BATCH * DM);
}

// Round 5
// 329.642 us; speedup vs baseline: 1.0528x; 1.0528x over previous
//
#include <hip/hip_runtime.h>

#define BATCH 4096
#define DM 768
#define LTOT 10240
#define NG 124

typedef __bf16 bf16x8 __attribute__((ext_vector_type(8)));
typedef short short8 __attribute__((ext_vector_type(8)));
typedef float f32x4 __attribute__((ext_vector_type(4)));

struct Ptr5 { const float* p[5]; };

__device__ __forceinline__ unsigned short f2bf(float f) {
    unsigned u = __builtin_bit_cast(unsigned, f);
    unsigned r = (u + 0x7FFFu + ((u >> 16) & 1u)) >> 16;   // RNE
    return (unsigned short)r;
}

__device__ __forceinline__ short8 pack8(float4 a, float4 b) {
    union { unsigned short u[8]; short8 s; } o;
    o.u[0] = f2bf(a.x); o.u[1] = f2bf(a.y); o.u[2] = f2bf(a.z); o.u[3] = f2bf(a.w);
    o.u[4] = f2bf(b.x); o.u[5] = f2bf(b.y); o.u[6] = f2bf(b.z); o.u[7] = f2bf(b.w);
    return o.s;
}

// ---------------- fat prep kernel (single dispatch, no atomics-needing-init) ----
// bx [0,32):       gate GEMM: relu(x@enc^T - b) -> gate_ws + d_out gates + slot stats
// bx [32,1952):    V{g}/U{g} conv (2048 float4/block), norm partial -> vslot/uslot
// bx [1952,2336):  x -> xb bf16 cast

__global__ __launch_bounds__(256) void prep_k(const float* __restrict__ x,
                                              Ptr5 vp, Ptr5 up, Ptr5 ep, Ptr5 bp,
                                              unsigned short* __restrict__ vb,
                                              unsigned short* __restrict__ w2t,
                                              unsigned short* __restrict__ xb,
                                              float* __restrict__ gate_ws,
                                              float* __restrict__ outg,
                                              float* __restrict__ vslot,
                                              float* __restrict__ uslot,
                                              float* __restrict__ gslot,
                                              float* __restrict__ aslot) {
    const int basen[5] = {0, 4, 12, 28, 60};
    int bx = blockIdx.x;
    int tid = threadIdx.x;
    if (bx < 32) {
        // ---- gate GEMM (M=128 rows per block, N=128 cols (124 valid), K=768) ----
        __shared__ unsigned short lA[128 * 64];
        __shared__ unsigned short lB[128 * 64];
        __shared__ float sgs[128];
        __shared__ float sac;
        int wave = tid >> 6, lane = tid & 63;
        int wm = wave >> 1, wn = wave & 1;
        int lan15 = lane & 15, quad = lane >> 4;
        int sw = lan15 & 7;
        int m0 = bx * 128;
        f32x4 acc[4][4] = {};
        for (int k0 = 0; k0 < DM; k0 += 64) {
            __syncthreads();
            #pragma unroll
            for (int i = 0; i < 4; i++) {
                int gidx = i * 256 + tid;           // granule index 0..1023
                int row = gidx >> 3, kb = gidx & 7;
                int r7 = row & 7;
                int la = (row >> 3) * 512 + r7 * 64 + (kb ^ r7) * 8;
                int sidx = (m0 + row) * 192 + (k0 >> 2) + kb * 2;
                float4 a0 = ((const float4*)x)[sidx];
                float4 a1 = ((const float4*)x)[sidx + 1];
                *(short8*)(lA + la) = pack8(a0, a1);
                float4 b0 = {0.f, 0.f, 0.f, 0.f}, b1 = {0.f, 0.f, 0.f, 0.f};
                if (row < NG) {
                    int g = (row < 4) ? 0 : (row < 12) ? 1 : (row < 28) ? 2 :
                            (row < 60) ? 3 : 4;
                    int ni = row - basen[g];
                    int eidx = ni * 192 + (k0 >> 2) + kb * 2;
                    b0 = ((const float4*)ep.p[g])[eidx];
                    b1 = ((const float4*)ep.p[g])[eidx + 1];
                }
                *(short8*)(lB + la) = pack8(b0, b1);
            }
            __syncthreads();
            #pragma unroll
            for (int kk = 0; kk < 2; kk++) {
                int kb = kk * 4 + quad;
                int kel = (kb ^ sw) * 8;
                bf16x8 af[4], bfr[4];
                #pragma unroll
                for (int t = 0; t < 4; t++) {
                    short8 ra = *(const short8*)(lA + (wm * 64 + t * 16 + lan15) * 64 + kel);
                    short8 rb = *(const short8*)(lB + (wn * 64 + t * 16 + lan15) * 64 + kel);
                    af[t]  = __builtin_bit_cast(bf16x8, ra);
                    bfr[t] = __builtin_bit_cast(bf16x8, rb);
                }
                #pragma unroll
                for (int mt = 0; mt < 4; mt++)
                    #pragma unroll
                    for (int nt = 0; nt < 4; nt++)
                        acc[mt][nt] = __builtin_amdgcn_mfma_f32_16x16x32_bf16(
                            af[mt], bfr[nt], acc[mt][nt], 0, 0, 0);
            }
        }
        if (tid < 128) sgs[tid] = 0.f;
        if (tid == 0) sac = 0.f;
        __syncthreads();
        const size_t baseg[5] = {3145730ull, 3145730ull + 16384, 3145730ull + 49152,
                                 3145730ull + 114688, 3145730ull + 245760};
        float cnt = 0.f;
        #pragma unroll
        for (int nt = 0; nt < 4; nt++) {
            int col = wn * 64 + nt * 16 + lan15;
            float cs = 0.f;
            if (col < NG) {
                int g = (col < 4) ? 0 : (col < 12) ? 1 : (col < 28) ? 2 :
                        (col < 60) ? 3 : 4;
                int ni = col - basen[g];
                int w = 4 << g;
                float bv = bp.p[g][ni];
                #pragma unroll
                for (int mt = 0; mt < 4; mt++) {
                    int r0 = m0 + wm * 64 + mt * 16 + quad * 4;
                    #pragma unroll
                    for (int rg = 0; rg < 4; rg++) {
                        float pre = acc[mt][nt][rg] - bv;
                        float gt = pre > 0.f ? pre : 0.f;
                        gate_ws[(size_t)(r0 + rg) * NG + col] = gt;
                        outg[baseg[g] + (size_t)(r0 + rg) * w + ni] = gt;
                        cs += gt;
                        if (pre > 0.f) cnt += 1.f;
                    }
                }
                cs += __shfl_xor(cs, 16);
                cs += __shfl_xor(cs, 32);
                if (quad == 0) atomicAdd(&sgs[col], cs);
            }
        }
        #pragma unroll
        for (int off = 32; off > 0; off >>= 1) cnt += __shfl_xor(cnt, off);
        if (lane == 0) atomicAdd(&sac, cnt);
        __syncthreads();
        if (tid < NG) gslot[bx * NG + tid] = sgs[tid];
        if (tid == 0) aslot[bx] = sac;
    } else if (bx < 1952) {
        // ---- streaming V/U conversion + norm slots ----
        __shared__ float swave[4];
        int cb = bx - 32;
        int isV = cb < 960;
        int wb = isV ? cb : cb - 960;       // 0..959
        int g = wb / 192;
        int within = wb - g * 192;
        const float* src = isV ? vp.p[g] : up.p[g];
        int r = 512 >> g, lr = 9 - g;
        float ss = 0.f;
        #pragma unroll
        for (int i = 0; i < 8; i++) {
            int j = within * 2048 + i * 256 + tid;
            float4 v = ((const float4*)src)[j];
            ss += v.x*v.x + v.y*v.y + v.z*v.z + v.w*v.w;
            ushort4 o;
            o.x = f2bf(v.x); o.y = f2bf(v.y); o.z = f2bf(v.z); o.w = f2bf(v.w);
            if (isV) {
                ((ushort4*)vb)[(size_t)(g * 192 + within) * 2048 + i * 256 + tid] = o;
            } else {
                int idx = j * 4;
                int rr = idx & (r - 1);
                int t2 = idx >> lr;
                int d  = t2 % DM;
                int n  = t2 / DM;
                size_t dst = (size_t)d * LTOT + (size_t)(g << 11) + (size_t)n * r + rr;
                *(ushort4*)(w2t + dst) = o;
            }
        }
        #pragma unroll
        for (int off = 32; off > 0; off >>= 1) ss += __shfl_down(ss, off);
        if ((tid & 63) == 0) swave[tid >> 6] = ss;
        __syncthreads();
        if (tid == 0) {
            float t = (swave[0] + swave[1]) + (swave[2] + swave[3]);
            (isV ? vslot : uslot)[wb] = t;
        }
    } else {
        // ---- x -> xb ----
        int base = (bx - 1952) * 2048;
        #pragma unroll
        for (int i = 0; i < 8; i++) {
            int j = base + i * 256 + tid;
            float4 v = ((const float4*)x)[j];
            ushort4 o;
            o.x = f2bf(v.x); o.y = f2bf(v.y); o.z = f2bf(v.z); o.w = f2bf(v.w);
            ((ushort4*)xb)[j] = o;
        }
    }
}

// ---------------- shared staging helper (XOR-swizzled async global->LDS) -------
template <int ROWS, int NT>
__device__ __forceinline__ void stage(const unsigned short* __restrict__ src, int ld,
                                      unsigned short* lds, int wv, int lane) {
    int rsub = lane >> 3;
    int colb = ((lane ^ rsub) & 7) * 8;
    #pragma unroll
    for (int i = 0; i < ROWS * 8 / NT; i++) {
        int c = i * (NT / 64) + wv;
        const unsigned short* gp = src + (size_t)(c * 8 + rsub) * ld + colb;
        __builtin_amdgcn_global_load_lds((const __attribute__((address_space(1))) void*)gp,
                                         (__attribute__((address_space(3))) void*)(lds + c * 512),
                                         16, 0, 0);
    }
}

// ---------------- GEMM1: 16x16x32 MFMA, gate + bf16 Hg LDS-transposed epilogue --
template <int BM, int BN, int NT>
__global__ __launch_bounds__(NT) void gemm_nt(const unsigned short* __restrict__ A,
                                              const unsigned short* __restrict__ Bm,
                                              int Kblk, int lda, int ldb,
                                              void* __restrict__ Cout,
                                              const float* __restrict__ gate, int ldc) {
    __shared__ unsigned short lA[BM * 64];
    __shared__ unsigned short lB[BN * 64];
    int tid = threadIdx.x, wave = tid >> 6, lane = tid & 63;
    constexpr int WN = BN / 64;
    int wm = wave / WN, wn = wave % WN;
    int m0 = blockIdx.x * BM, n0 = blockIdx.y * BN;    // m is the FAST grid dim
    A  += (size_t)m0 * lda;
    Bm += (size_t)n0 * ldb;
    f32x4 acc[4][4] = {};
    int lan15 = lane & 15, quad = lane >> 4;
    int sw = lan15 & 7;

    for (int k0 = 0; k0 < Kblk; k0 += 64) {
        stage<BM, NT>(A + k0, lda, lA, wave, lane);
        stage<BN, NT>(Bm + k0, ldb, lB, wave, lane);
        __syncthreads();
        #pragma unroll
        for (int kk = 0; kk < 2; kk++) {
            int kb = kk * 4 + quad;
            int kel = (kb ^ sw) * 8;
            bf16x8 af[4], bfr[4];
            #pragma unroll
            for (int t = 0; t < 4; t++) {
                short8 ra = *(const short8*)(lA + (size_t)(wm * 64 + t * 16 + lan15) * 64 + kel);
                short8 rb = *(const short8*)(lB + (size_t)(wn * 64 + t * 16 + lan15) * 64 + kel);
                af[t]  = __builtin_bit_cast(bf16x8, ra);
                bfr[t] = __builtin_bit_cast(bf16x8, rb);
            }
            #pragma unroll
            for (int mt = 0; mt < 4; mt++)
                #pragma unroll
                for (int nt = 0; nt < 4; nt++)
                    acc[mt][nt] = __builtin_amdgcn_mfma_f32_16x16x32_bf16(af[mt], bfr[nt],
                                                                          acc[mt][nt], 0, 0, 0);
        }
        __syncthreads();
    }

    const int basen[5] = {0, 4, 12, 28, 60};
    unsigned short* H = (unsigned short*)Cout;
    #pragma unroll
    for (int mt = 0; mt < 4; mt++) {
        __syncthreads();
        #pragma unroll
        for (int nt = 0; nt < 4; nt++) {
            int col = n0 + wn * 64 + nt * 16 + lan15;
            int g = col >> 11;
            int ngl = basen[g] + ((col & 2047) >> (9 - g));
            #pragma unroll
            for (int rg = 0; rg < 4; rg++) {
                int grow = m0 + wm * 64 + mt * 16 + quad * 4 + rg;
                float gv = gate[(size_t)grow * NG + ngl];
                lA[wave * 1024 + (quad * 4 + rg) * 64 + nt * 16 + lan15] =
                    f2bf(acc[mt][nt][rg] * gv);
            }
        }
        __syncthreads();
        #pragma unroll
        for (int i = 0; i < 2; i++) {
            int f = i * NT + tid;
            int R = f >> 5;
            int u = f & 31;
            int wv2 = ((R >> 4) << 2) + (u >> 3);
            short8 vread = *(const short8*)(lA + wv2 * 1024 + (R & 15) * 64 + (u & 7) * 8);
            int grow = m0 + (R >> 4) * 64 + mt * 16 + (R & 15);
            *(short8*)(H + (size_t)grow * ldc + n0 + u * 8) = vread;
        }
    }
}

// ---------------- GEMM2: 8-phase 256x256 template (T2+T3+T4+T5) ----------------
// 512 thr / 8 waves (2Mx4N), per-wave 128x64 out (acc[8][4]), BK=64 as 2 k-halves
// of 32. LDS 128KB = A[2buf][2kh][256][32] + B[...]. Per K-tile: 4 phases, each
// {ds_read 4-8 b128, stage 1 half-tile (2 gload/thr), bar, lgkmcnt(0)+schedbar,
// setprio(1), 16 MFMA, setprio(0), bar}. Staging runs 6-7 phases ahead of first
// read; vmcnt(6) (=3 half-tiles outstanding) once per K-tile before phase-2's
// 2nd barrier — NEVER drained in the loop. Ledger (verified): A-half staged at
// global phase q first-read q+6; B-half at q (even) first-read q+7; wait at
// q==2 mod 4 guarantees landed <= q-4 (counting 2 loads/half). Bank-conflict
// fix for 64B rows: LDS granule = src_granule ^ ((row>>1)&3) -> each quad's 16
// lanes cover all 8 16B slots (2/slot = free). Slot rolling-reuse is race-free:
// each stage targets a slot last read a full barrier earlier (B frags held in
// regs across the msub1 phase). r4 failure root-caused: 1-phase prefetch depth
// + 4-way read conflicts; both fixed here.
__global__ __launch_bounds__(512, 1) void gemm2_nt(const unsigned short* __restrict__ A,
                                                   const unsigned short* __restrict__ Bm,
                                                   float* __restrict__ P) {
    __shared__ unsigned short lds[65536];   // A: [0,32768) ; B: [32768,65536)
    const int tid = threadIdx.x;
    const int wave = tid >> 6, lane = tid & 63;
    const int wm = wave >> 2, wn = wave & 3;
    const int lan15 = lane & 15, quad = lane >> 4;
    const int swz = quad ^ ((lan15 >> 1) & 3);
    const int m0 = blockIdx.x * 256, n0 = blockIdx.y * 256;
    const unsigned short* Ab = A  + (size_t)m0 * LTOT + blockIdx.z * 2048;
    const unsigned short* Bb = Bm + (size_t)n0 * LTOT + blockIdx.z * 2048;
    const int srow = lane >> 2;                         // staging: row within chunk
    const int sgr  = (lane & 3) ^ ((lane >> 3) & 3);    // staging: swizzled src granule
    const int rdA = (wm * 128 + lan15) * 32 + swz * 8;
    const int rdB = 32768 + (wn * 64 + lan15) * 32 + swz * 8;

    // stage one half-tile (256 rows x 32 k) into lds[base .. base+8192)
#define STG(base_us, gb, koff) do { \
    const unsigned short* _s0 = (gb) + (size_t)(wave * 16 + srow) * LTOT + (koff) + sgr * 8; \
    const unsigned short* _s1 = (gb) + (size_t)((wave + 8) * 16 + srow) * LTOT + (koff) + sgr * 8; \
    __builtin_amdgcn_global_load_lds((const __attribute__((address_space(1))) void*)_s0, \
        (__attribute__((address_space(3))) void*)(lds + (base_us) + wave * 512), 16, 0, 0); \
    __builtin_amdgcn_global_load_lds((const __attribute__((address_space(1))) void*)_s1, \
        (__attribute__((address_space(3))) void*)(lds + (base_us) + (wave + 8) * 512), 16, 0, 0); \
} while (0)
#define STGA(buf, kh, koff) STG(((buf) * 2 + (kh)) * 8192, Ab, koff)
#define STGB(buf, kh, koff) STG(32768 + ((buf) * 2 + (kh)) * 8192, Bb, koff)

#define RDA(msub, bufkg) { \
    _Pragma("unroll") for (int t = 0; t < 4; t++) \
        af[t] = __builtin_bit_cast(bf16x8, \
            *(const short8*)(lds + (bufkg) * 8192 + rdA + ((msub) * 64 + t * 16) * 32)); }
#define RDB(bufkg) { \
    _Pragma("unroll") for (int t = 0; t < 4; t++) \
        bf[t] = __builtin_bit_cast(bf16x8, \
            *(const short8*)(lds + 32768 + (bufkg) * 8192 + rdB - 32768 + t * 512)); }
#define SYNC1 do { __builtin_amdgcn_s_barrier(); \
    asm volatile("s_waitcnt lgkmcnt(0)" ::: "memory"); \
    __builtin_amdgcn_sched_barrier(0); } while (0)
#define MM(msub) do { __builtin_amdgcn_s_setprio(1); \
    _Pragma("unroll") for (int mt = 0; mt < 4; mt++) \
        _Pragma("unroll") for (int nf = 0; nf < 4; nf++) \
            acc[(msub) * 4 + mt][nf] = __builtin_amdgcn_mfma_f32_16x16x32_bf16( \
                af[mt], bf[nf], acc[(msub) * 4 + mt][nf], 0, 0, 0); \
    __builtin_amdgcn_s_setprio(0); } while (0)
#define SYNC2 do { asm volatile("" ::: "memory"); __builtin_amdgcn_s_barrier(); \
    asm volatile("" ::: "memory"); } while (0)

    f32x4 acc[8][4] = {};
    // prologue: 7 half-tiles, oldest-first; vmcnt(10) leaves 5 halves in flight
    STGA(0, 0, 0);  STGB(0, 0, 0);
    STGA(0, 1, 32); STGB(0, 1, 32);
    STGA(1, 0, 64); STGB(1, 0, 64);
    STGB(1, 1, 96);
    asm volatile("s_waitcnt vmcnt(10)" ::: "memory");
    __builtin_amdgcn_s_barrier();

    for (int i = 0; i < 32; i++) {
        const int buf = i & 1;
        bf16x8 af[4], bf[4];
        // phase 1: msub0, kg0; stage A[buf^1][k1] for tile i+1
        RDA(0, buf * 2 + 0); RDB(buf * 2 + 0);
        if (i + 1 < 32) STGA(buf ^ 1, 1, (i + 1) * 64 + 32);
        SYNC1; MM(0); SYNC2;
        // phase 2: msub1, kg0; stage B[buf][k0] for tile i+2; counted vmcnt
        RDA(1, buf * 2 + 0);
        if (i + 2 < 32) STGB(buf, 0, (i + 2) * 64);
        SYNC1; MM(1);
        asm volatile("s_waitcnt vmcnt(6)" ::: "memory");
        SYNC2;
        // phase 3: msub0, kg1; stage A[buf][k0] for tile i+2
        RDA(0, buf * 2 + 1); RDB(buf * 2 + 1);
        if (i + 2 < 32) STGA(buf, 0, (i + 2) * 64);
        SYNC1; MM(0); SYNC2;
        // phase 4: msub1, kg1; stage B[buf][k1] for tile i+2
        RDA(1, buf * 2 + 1);
        if (i + 2 < 32) STGB(buf, 1, (i + 2) * 64 + 32);
        SYNC1; MM(1); SYNC2;
    }
    asm volatile("s_waitcnt vmcnt(0)" ::: "memory");
#undef STG
#undef STGA
#undef STGB
#undef RDA
#undef RDB
#undef SYNC1
#undef SYNC2
#undef MM

    float* Pz = P + (size_t)blockIdx.z * ((size_t)BATCH * DM);
    #pragma unroll
    for (int mf = 0; mf < 8; mf++) {
        #pragma unroll
        for (int rg = 0; rg < 4; rg++) {
            int row = m0 + wm * 128 + mf * 16 + quad * 4 + rg;
            float* pr = Pz + (size_t)row * DM + n0 + wn * 64 + lan15;
            #pragma unroll
            for (int nf = 0; nf < 4; nf++)
                pr[nf * 16] = acc[mf][nf][rg];
        }
    }
}

// ---------------- split-K (5-way) reduce + fused final stats (block 0) ---------

__global__ __launch_bounds__(256) void reduce_k(const float4* __restrict__ P,
                                                float4* __restrict__ out, int quarter,
                                                const float* __restrict__ vslot,
                                                const float* __restrict__ uslot,
                                                const float* __restrict__ gslot,
                                                const float* __restrict__ aslot,
                                                float* __restrict__ o2) {
    int i = blockIdx.x * 256 + threadIdx.x;
    float4 a = P[i], b = P[i + quarter], c = P[i + 2 * quarter], d = P[i + 3 * quarter];
    float4 e = P[i + 4 * quarter];
    float4 o;
    o.x = ((a.x + b.x) + (c.x + d.x)) + e.x;
    o.y = ((a.y + b.y) + (c.y + d.y)) + e.y;
    o.z = ((a.z + b.z) + (c.z + d.z)) + e.z;
    o.w = ((a.w + b.w) + (c.w + d.w)) + e.w;
    out[i] = o;
    if (blockIdx.x == 0) {
        __shared__ float sh[128];
        const int basen[5] = {0, 4, 12, 28, 60};
        int t = threadIdx.x;
        if (t < 128) {
            float v = 0.f;
            if (t < NG) {
                int g = (t < 4) ? 0 : (t < 12) ? 1 : (t < 28) ? 2 : (t < 60) ? 3 : 4;
                int nloc = t - basen[g];
                int bpseg = 48 >> g;
                float vs = 0.f, us = 0.f;
                int base = g * 192 + nloc * bpseg;
                for (int j = 0; j < bpseg; j++) { vs += vslot[base + j]; us += uslot[base + j]; }
                float gs = 0.f;
                for (int bb = 0; bb < 32; bb++) gs += gslot[bb * NG + t];
                float rr = (float)(512 >> g);
                float mean = gs * (1.0f / BATCH);
                float frob = sqrtf(us * vs) / sqrtf(768.0f * rr);
                v = tanhf(mean) * frob;
            }
            sh[t] = v;
        }
        if (t == 128) {
            float asum = 0.f;
            for (int bb = 0; bb < 32; bb++) asum += aslot[bb];
            o2[1] = asum * (1.0f / BATCH);
        }
        __syncthreads();
        for (int s = 64; s > 0; s >>= 1) {
            if (threadIdx.x < s) sh[threadIdx.x] += sh[threadIdx.x + s];
            __syncthreads();
        }
        if (threadIdx.x == 0) o2[0] = sh[0];
    }
}

// ---------------- launcher ----------------
// Workspace: w2t (15.73) | slots (~0.03) | Hg (83.9) | partial 5*12.58 = 62.9
// xb/vb/gate_ws ALIASED into the partial region (dead after gemm1; partial
// written only by gemm2, stream-ordered after). Single-chunk (CB == BATCH).

extern "C" void kernel_launch(void* const* d_in, const int* in_sizes, int n_in,
                              void* d_out, int out_size, void* d_ws, size_t ws_size,
                              hipStream_t stream) {
    const float* x = (const float*)d_in[0];
    Ptr5 vp, up, ep, bp;
    for (int g = 0; g < 5; g++) {
        vp.p[g] = (const float*)d_in[1 + 4 * g];
        up.p[g] = (const float*)d_in[2 + 4 * g];
        ep.p[g] = (const float*)d_in[3 + 4 * g];
        bp.p[g] = (const float*)d_in[4 + 4 * g];
    }
    float* out = (float*)d_out;
    char* ws = (char*)d_ws;
    size_t off = 0;
    unsigned short* w2t  = (unsigned short*)(ws + off); off += (size_t)LTOT * DM * 2;
    float* vslot         = (float*)(ws + off);          off += 960 * 4;
    float* uslot         = (float*)(ws + off);          off += 960 * 4;
    float* gslot         = (float*)(ws + off);          off += 32 * NG * 4;
    float* aslot         = (float*)(ws + off);          off += 32 * 4 + 256;
    unsigned short* Hg   = (unsigned short*)(ws + off); off += (size_t)BATCH * LTOT * 2;
    float* partial       = (float*)(ws + off);          off += 5ull * BATCH * DM * 4;
    // aliases inside the partial region (24.1 MB used of 62.9):
    unsigned short* xb      = (unsigned short*)partial;
    unsigned short* vb      = (unsigned short*)((char*)partial + (size_t)BATCH * DM * 2);
    float* gate_ws          = (float*)((char*)partial + (size_t)BATCH * DM * 2
                                                      + (size_t)LTOT * DM * 2);

    prep_k<<<dim3(2336), 256, 0, stream>>>(
        x, vp, up, ep, bp, vb, w2t, xb, gate_ws, out,
        vslot, uslot, gslot, aslot);

    // GEMM1: Hg = gate .* (x @ V^T)   (M=4096, N=10240, K=768), m-fast grid
    gemm_nt<128, 256, 512><<<dim3(BATCH / 128, LTOT / 256, 1), 512, 0, stream>>>(
        xb, vb, DM, DM, DM, (void*)Hg, gate_ws, LTOT);
    // GEMM2: out = Hg @ W2   (M=4096, N=768, K=10240), split-K=5, 8-phase 256^2
    gemm2_nt<<<dim3(BATCH / 256, DM / 256, 5), 512, 0, stream>>>(Hg, w2t, partial);
    // 5-way reduce + fused final stats (block 0)
    reduce_k<<<dim3(BATCH * DM / 4 / 256), 256, 0, stream>>>(
        (const float4*)partial, (float4*)out, BATCH * DM / 4,
        vslot, uslot, gslot, aslot, out + (size_t)BATCH * DM);
}